// Round 13
// baseline (60.602 us; speedup 1.0000x reference)
//
#include <hip/hip_runtime.h>

// HBV hydrological model, MI355X (gfx950).
// x (365,1000,3) f32, parameters (365,1000,14,16) f32, staind i32 -> out (365,1000,1) f32.
//
// Latency-bound serial scan (250 waves, 1 wave/CU). Model (calibrated R8/R12): the
// scheduler emits the step in dependence order; every spine op pays full latency
// (~5-8cy), total ~383cy/step vs ~130cy issue floor. R13: pin a hand-zipped emission
// order with __builtin_amdgcn_sched_barrier(0) fences -- trans heads early, independent
// snow/response ops packed into their latency shadows. Step is pure VALU (loads/LDS
// writes stay outside the fenced region), so m141's waitcnt pathology doesn't apply.
// Math bit-identical to R12.
// Carried: R11 register banks, R12 spine surgery, deferred mu-reduce, LDS-staged out.

static constexpr int   NSTEP = 365;
static constexpr int   NGRID = 1000;
static constexpr int   MU    = 16;
static constexpr float PRECS = 1e-5f;
static constexpr int   QPAD  = 68;     // qlds row stride (words): 64 + 4 pad

#define SB() __builtin_amdgcn_sched_barrier(0)

__global__ __launch_bounds__(64)
__attribute__((amdgpu_waves_per_eu(1, 1)))
void hbv_kernel(const float* __restrict__ x,
                const float* __restrict__ par,
                const int*   __restrict__ staind_p,
                float*       __restrict__ out)
{
    __shared__ float qlds[NSTEP * QPAD];   // 99,280 B: per-lane Q per step

    const int lane = threadIdx.x;          // 0..63
    const int m    = lane & 15;            // mu index
    const int gl   = lane >> 4;            // 0..3 local g
    const int gbase = blockIdx.x * 4;
    const int g    = gbase + gl;
    const int staind = *staind_p;

    const size_t tstride = (size_t)NGRID * 14 * MU;
    const int    xstride = NGRID * 3;
    const int    lp = g * (14 * MU) + m;   // per-lane param offset within a step row
    const int    lx = g * 3;               // per-lane x offset within a step row

    // ---- static params: parameters[staind, g, i, m] ----
    const float* ps = par + (size_t)staind * tstride + lp;
    const float FC    = 50.0f  + ps[ 1*MU] * (1000.0f - 50.0f);
    const float K0    = 0.05f  + ps[ 2*MU] * (0.9f  - 0.05f);
    const float K1    = 0.01f  + ps[ 3*MU] * (0.5f  - 0.01f);
    const float K2    = 0.001f + ps[ 4*MU] * (0.2f  - 0.001f);
    const float LP    = 0.2f   + ps[ 5*MU] * (1.0f  - 0.2f);
    const float PERCp =          ps[ 6*MU] * 10.0f;
    const float UZL   =          ps[ 7*MU] * 100.0f;
    const float TT    = -2.5f  + ps[ 8*MU] * 5.0f;
    const float CFMAX = 0.5f   + ps[ 9*MU] * (10.0f - 0.5f);
    const float CRF   =          ps[10*MU] * 0.1f * CFMAX;
    const float CWH   =          ps[11*MU] * 0.2f;
    const float C     =          ps[13*MU] * 1.0f;
    const float rFC   = 1.0f / FC;
    const float lgFC   = __builtin_amdgcn_logf(FC);
    const float dlg    = lgFC - __builtin_amdgcn_logf(LP * FC);  // log2(1/LP) >= 0
    const float K1c    = 1.0f - K1;
    const float K2c    = 1.0f - K2;

    // ---- state ----
    float SP = 1e-3f, MW = 1e-3f, SM = 1e-3f, SUZ = 1e-3f, SLZ = 1e-3f;

    auto step = [&](float P, float T, float E, float p0, float p12) -> float {
        // G0: input-only prep + off-spine precompute (all parallel)
        const float BETA   = fmaf(p0, 5.0f, 1.0f);
        const float BETAET = fmaf(p12, 4.7f, 0.3f);
        const float dT     = T - TT;
        const float acap   = CFMAX * dT;
        const float bcap   = CRF * (-dT);
        const bool  rc     = (T >= TT);
        const float RAIN   = rc ? P : 0.0f;
        const float SNOW   = rc ? 0.0f : P;
        const float CSLZ   = C * SLZ;              // SLZ ready since prev step
        SB();
        // G1: trans head (log latency shadow starts) + parallel snow/soil openers
        const float lg     = __builtin_amdgcn_logf(SM);
        const float SP1    = SP + SNOW;
        const float excess = fmaxf(SM - FC, 0.0f);
        const float SM1    = fminf(SM, FC);
        SB();
        // G2: (log shadow) snow continues
        const float melt   = __builtin_amdgcn_fmed3f(acap, 0.0f, SP1);
        const float SUZe   = SUZ + excess;
        SB();
        // G3: first log consumer + snow
        const float u      = lg - lgFC;
        const float SP2    = SP1 - melt;
        const float MW1    = MW + melt;
        SB();
        // G4
        const float uc     = fminf(u, 0.0f);
        const float te     = u + dlg;              // min(uc+dlg,0)==min(u+dlg,0), dlg>=0
        const float refr   = __builtin_amdgcn_fmed3f(bcap, 0.0f, MW1);
        SB();
        // G5
        const float wz     = BETA * uc;
        const float tec    = fminf(te, 0.0f);
        const float MW2    = MW1 - refr;
        const float SP3    = SP2 + refr;
        SB();
        // G6: exp2 heads back-to-back; snow tail fills their shadow
        const float wet    = __builtin_amdgcn_exp2f(wz);
        const float ez     = BETAET * tec;
        const float lim    = CWH * SP3;
        SB();
        // G7
        const float evapf  = __builtin_amdgcn_exp2f(ez);
        const float tosoil = fmaxf(MW2 - lim, 0.0f);
        SB();
        // G8: (exp2 shadows) state commits + rt
        const float rt     = RAIN + tosoil;
        SP = SP3;
        MW = fminf(MW2, lim);
        SB();
        // G9: consumers of both exp2 results
        const float recharge = rt * wet;
        const float SM2      = fmaxf(fmaf(-E, evapf, SM1), PRECS);
        const float smrt     = SM2 + rt;
        SB();
        // G10
        const float SM3    = smrt - recharge;
        const float SUZ1   = SUZe + recharge;
        SB();
        // G11
        const float capf   = fmaxf(fmaf(-SM3, rFC, 1.0f), 0.0f);
        const float PERC   = fminf(SUZ1, PERCp);
        SB();
        // G12
        const float capr   = CSLZ * capf;
        const float SUZ2   = SUZ1 - PERC;
        SB();
        // G13
        const float cap    = fminf(SLZ, capr);
        const float q0a    = fmaxf(SUZ2 - UZL, 0.0f);
        SB();
        // G14
        SM = fmaxf(SM3 + cap, PRECS);
        const float SLZ1   = fmaxf(SLZ - cap, PRECS);
        const float Q0     = K0 * q0a;
        SB();
        // G15
        const float SUZ3   = SUZ2 - Q0;
        const float SLZ2   = SLZ1 + PERC;
        SB();
        // G16: tail (independent pairs)
        const float Q1     = K1 * SUZ3;
        SUZ = K1c * SUZ3;
        const float Q2     = K2 * SLZ2;
        SLZ = K2c * SLZ2;
        const float q02    = Q0 + Q2;
        SB();
        return q02 + Q1;
    };

    // ---- double-buffered register banks (all statically indexed via macros) ----
    float aP[10], aT[10], aE[10], a0[10], a12[10];
    float cP[10], cT[10], cE[10], c0[10], c12[10];
    const float* prow = par;   // uniform step-row base, advances tstride per row
    const float* xrow = x;     // uniform step-row base, advances xstride per row

#define LOADB(BP, BT, BE, B0, B12, N)                            \
    _Pragma("unroll") for (int j = 0; j < (N); ++j) {            \
        B0[j]  = prow[lp];                                       \
        B12[j] = prow[lp + 192];                                 \
        const float3 v = *(const float3*)(xrow + lx);            \
        BP[j] = v.x; BT[j] = v.y; BE[j] = v.z;                   \
        prow += tstride; xrow += xstride;                        \
    }

#define COMPB(BP, BT, BE, B0, B12, T0, N)                        \
    {                                                            \
        float qreg[10];                                          \
        _Pragma("unroll") for (int j = 0; j < (N); ++j)          \
            qreg[j] = step(BP[j], BT[j], BE[j], B0[j], B12[j]);  \
        _Pragma("unroll") for (int j = 0; j < (N); ++j)          \
            qlds[((T0) + j) * QPAD + lane] = qreg[j];            \
    }

    LOADB(aP, aT, aE, a0, a12, 10)             // rows 0..9

    for (int bb = 0; bb < 17; ++bb) {          // 17 double-blocks = steps 0..339
        const int t0 = bb * 20;
        LOADB(cP, cT, cE, c0, c12, 10)         // rows t0+10 .. t0+19
        COMPB(aP, aT, aE, a0, a12, t0, 10)     // steps t0 .. t0+9 (pure ALU)
        LOADB(aP, aT, aE, a0, a12, 10)         // rows t0+20 .. t0+29
        COMPB(cP, cT, cE, c0, c12, t0 + 10, 10)
    }
    // invariant: bank a holds rows 340..349, prow at row 350

    LOADB(cP, cT, cE, c0, c12, 10)             // rows 350..359
    COMPB(aP, aT, aE, a0, a12, 340, 10)        // steps 340..349
    LOADB(aP, aT, aE, a0, a12, 5)              // rows 360..364
    COMPB(cP, cT, cE, c0, c12, 350, 10)        // steps 350..359
    COMPB(aP, aT, aE, a0, a12, 360, 5)         // steps 360..364

#undef LOADB
#undef COMPB

    // ---- flush: 16-lane sums + coalesced global stores (1 wave/block, no barrier;
    //      compiler inserts the lgkmcnt wait before the LDS reads) ----
    for (int i = lane; i < NSTEP * 4; i += 64) {
        const int t  = i >> 2;
        const int gg = i & 3;
        const float* row = &qlds[t * QPAD + gg * 16];
        float s = 0.0f;
#pragma unroll
        for (int k = 0; k < 16; ++k) s += row[k];
        out[t * NGRID + gbase + gg] = s * 0.0625f;
    }
}

extern "C" void kernel_launch(void* const* d_in, const int* in_sizes, int n_in,
                              void* d_out, int out_size, void* d_ws, size_t ws_size,
                              hipStream_t stream) {
    const float* x      = (const float*)d_in[0];
    const float* par    = (const float*)d_in[1];
    const int*   staind = (const int*)d_in[2];
    float*       out    = (float*)d_out;

    hipLaunchKernelGGL(hbv_kernel, dim3(NGRID / 4), dim3(64), 0, stream,
                       x, par, staind, out);
}

// Round 14
// 53.359 us; speedup vs baseline: 1.1357x; 1.1357x over previous
//
#include <hip/hip_runtime.h>

// HBV hydrological model, MI355X (gfx950).
// x (365,1000,3) f32, parameters (365,1000,14,16) f32, staind i32 -> out (365,1000,1) f32.
//
// Latency-bound sequential scan (250 waves, 1 wave/CU). Consolidated model (R5/R8/
// R12/R13): single-wave issue cadence ~4cy/instr x ~57 instr/step + trans residual
// ~= 380cy/step; compiler schedule already near-optimal (R13: pinning order hurt).
// Only lever left: delete semantically unnecessary instructions.
// R14: (1) cap = C*SLZ*capf -- the min(SLZ,.) NEVER binds (C<=1, capf<=1, f32-safe);
// (2) Q0 = max(fma(K0,SUZ2,-K0*UZL),0) with K0*UZL hoisted; (3) excess eliminated via
// SUZe = (SUZ+SM) - min(SM,FC). Sched barriers reverted (R13 regression).
// Carried: R11 register banks, R12 spine surgery, deferred mu-reduce, LDS-staged out.

static constexpr int   NSTEP = 365;
static constexpr int   NGRID = 1000;
static constexpr int   MU    = 16;
static constexpr float PRECS = 1e-5f;
static constexpr int   QPAD  = 68;     // qlds row stride (words): 64 + 4 pad

__global__ __launch_bounds__(64)
__attribute__((amdgpu_waves_per_eu(1, 1)))
void hbv_kernel(const float* __restrict__ x,
                const float* __restrict__ par,
                const int*   __restrict__ staind_p,
                float*       __restrict__ out)
{
    __shared__ float qlds[NSTEP * QPAD];   // 99,280 B: per-lane Q per step

    const int lane = threadIdx.x;          // 0..63
    const int m    = lane & 15;            // mu index
    const int gl   = lane >> 4;            // 0..3 local g
    const int gbase = blockIdx.x * 4;
    const int g    = gbase + gl;
    const int staind = *staind_p;

    const size_t tstride = (size_t)NGRID * 14 * MU;
    const int    xstride = NGRID * 3;
    const int    lp = g * (14 * MU) + m;   // per-lane param offset within a step row
    const int    lx = g * 3;               // per-lane x offset within a step row

    // ---- static params: parameters[staind, g, i, m] ----
    const float* ps = par + (size_t)staind * tstride + lp;
    const float FC    = 50.0f  + ps[ 1*MU] * (1000.0f - 50.0f);
    const float K0    = 0.05f  + ps[ 2*MU] * (0.9f  - 0.05f);
    const float K1    = 0.01f  + ps[ 3*MU] * (0.5f  - 0.01f);
    const float K2    = 0.001f + ps[ 4*MU] * (0.2f  - 0.001f);
    const float LP    = 0.2f   + ps[ 5*MU] * (1.0f  - 0.2f);
    const float PERCp =          ps[ 6*MU] * 10.0f;
    const float UZL   =          ps[ 7*MU] * 100.0f;
    const float TT    = -2.5f  + ps[ 8*MU] * 5.0f;
    const float CFMAX = 0.5f   + ps[ 9*MU] * (10.0f - 0.5f);
    const float CRF   =          ps[10*MU] * 0.1f * CFMAX;
    const float CWH   =          ps[11*MU] * 0.2f;
    const float C     =          ps[13*MU] * 1.0f;
    const float rFC   = 1.0f / FC;
    const float lgFC   = __builtin_amdgcn_logf(FC);
    const float dlg    = lgFC - __builtin_amdgcn_logf(LP * FC);  // log2(1/LP) >= 0
    const float K1c    = 1.0f - K1;
    const float K2c    = 1.0f - K2;
    const float nK0UZL = -K0 * UZL;

    // ---- state ----
    float SP = 1e-3f, MW = 1e-3f, SM = 1e-3f, SUZ = 1e-3f, SLZ = 1e-3f;

    auto step = [&](float P, float T, float E, float p0, float p12) -> float {
        // off-chain prep
        const float BETA    = fmaf(p0, 5.0f, 1.0f);
        const float BETAET  = fmaf(p12, 4.7f, 0.3f);
        const float dT      = T - TT;
        const float acap    = CFMAX * dT;        // raw; med3 clamps
        const float bcap    = CRF * (-dT);       // raw; med3 clamps
        const bool  rc      = (T >= TT);
        const float RAIN    = rc ? P : 0.0f;
        const float SNOW    = rc ? 0.0f : P;
        const float smsuz   = SUZ + SM;          // for SUZe (excess eliminated)

        // snow module (SP, MW)
        const float SP1  = SP + SNOW;
        const float melt = __builtin_amdgcn_fmed3f(acap, 0.0f, SP1);  // SP1 >= 0
        const float SP2  = SP1 - melt;
        const float MW1  = MW + melt;
        const float refr = __builtin_amdgcn_fmed3f(bcap, 0.0f, MW1);  // MW1 >= 0
        const float MW2  = MW1 - refr;
        const float SP3  = SP2 + refr;
        const float lim  = CWH * SP3;
        const float tosoil = fmaxf(MW2 - lim, 0.0f);
        SP = SP3;
        MW = fminf(MW2, lim);                    // MW2 - tosoil (exact)

        // soil module -- shared log-domain clamp for both pows
        const float SM1    = fminf(SM, FC);            // SM - excess (exact)
        const float SUZe   = smsuz - SM1;              // SUZ + excess (ulp-level)
        const float lg     = __builtin_amdgcn_logf(SM);        // log2(SM), SM >= PRECS
        const float uc     = fminf(lg - lgFC, 0.0f);           // min(log2(SM/FC), 0)
        const float wet    = __builtin_amdgcn_exp2f(BETA * uc);
        const float evapf  = __builtin_amdgcn_exp2f(BETAET * fminf(uc + dlg, 0.0f));
        const float SM2    = fmaxf(fmaf(-E, evapf, SM1), PRECS);  // ETact fold (exact)
        const float rt     = RAIN + tosoil;
        const float recharge = rt * wet;
        const float SM3    = (SM2 + rt) - recharge;
        const float capf   = fmaxf(fmaf(-SM3, rFC, 1.0f), 0.0f);
        const float cap    = (C * SLZ) * capf;   // min(SLZ, .) never binds: C,capf <= 1
        SM = fmaxf(SM3 + cap, PRECS);
        const float SLZ1   = fmaxf(SLZ - cap, PRECS);

        // response
        const float SUZ1 = SUZe + recharge;
        const float PERC = fminf(SUZ1, PERCp);
        const float SUZ2 = SUZ1 - PERC;
        const float Q0   = fmaxf(fmaf(K0, SUZ2, nK0UZL), 0.0f);   // K0*max(SUZ2-UZL,0)
        const float SUZ3 = SUZ2 - Q0;
        const float Q1   = K1 * SUZ3;     // independent pair:
        SUZ = K1c * SUZ3;                 // SUZ3 - Q1 (ulp-level)
        const float SLZ2 = SLZ1 + PERC;
        const float Q2   = K2 * SLZ2;     // independent pair:
        SLZ = K2c * SLZ2;                 // SLZ2 - Q2 (ulp-level)

        return Q0 + Q1 + Q2;
    };

    // ---- double-buffered register banks (all statically indexed via macros) ----
    float aP[10], aT[10], aE[10], a0[10], a12[10];
    float cP[10], cT[10], cE[10], c0[10], c12[10];
    const float* prow = par;   // uniform step-row base, advances tstride per row
    const float* xrow = x;     // uniform step-row base, advances xstride per row

#define LOADB(BP, BT, BE, B0, B12, N)                            \
    _Pragma("unroll") for (int j = 0; j < (N); ++j) {            \
        B0[j]  = prow[lp];                                       \
        B12[j] = prow[lp + 192];                                 \
        const float3 v = *(const float3*)(xrow + lx);            \
        BP[j] = v.x; BT[j] = v.y; BE[j] = v.z;                   \
        prow += tstride; xrow += xstride;                        \
    }

#define COMPB(BP, BT, BE, B0, B12, T0, N)                        \
    {                                                            \
        float qreg[10];                                          \
        _Pragma("unroll") for (int j = 0; j < (N); ++j)          \
            qreg[j] = step(BP[j], BT[j], BE[j], B0[j], B12[j]);  \
        _Pragma("unroll") for (int j = 0; j < (N); ++j)          \
            qlds[((T0) + j) * QPAD + lane] = qreg[j];            \
    }

    LOADB(aP, aT, aE, a0, a12, 10)             // rows 0..9

    for (int bb = 0; bb < 17; ++bb) {          // 17 double-blocks = steps 0..339
        const int t0 = bb * 20;
        LOADB(cP, cT, cE, c0, c12, 10)         // rows t0+10 .. t0+19
        COMPB(aP, aT, aE, a0, a12, t0, 10)     // steps t0 .. t0+9 (pure ALU)
        LOADB(aP, aT, aE, a0, a12, 10)         // rows t0+20 .. t0+29
        COMPB(cP, cT, cE, c0, c12, t0 + 10, 10)
    }
    // invariant: bank a holds rows 340..349, prow at row 350

    LOADB(cP, cT, cE, c0, c12, 10)             // rows 350..359
    COMPB(aP, aT, aE, a0, a12, 340, 10)        // steps 340..349
    LOADB(aP, aT, aE, a0, a12, 5)              // rows 360..364
    COMPB(cP, cT, cE, c0, c12, 350, 10)        // steps 350..359
    COMPB(aP, aT, aE, a0, a12, 360, 5)         // steps 360..364

#undef LOADB
#undef COMPB

    // ---- flush: 16-lane sums + coalesced global stores (1 wave/block, no barrier;
    //      compiler inserts the lgkmcnt wait before the LDS reads) ----
    for (int i = lane; i < NSTEP * 4; i += 64) {
        const int t  = i >> 2;
        const int gg = i & 3;
        const float* row = &qlds[t * QPAD + gg * 16];
        float s = 0.0f;
#pragma unroll
        for (int k = 0; k < 16; ++k) s += row[k];
        out[t * NGRID + gbase + gg] = s * 0.0625f;
    }
}

extern "C" void kernel_launch(void* const* d_in, const int* in_sizes, int n_in,
                              void* d_out, int out_size, void* d_ws, size_t ws_size,
                              hipStream_t stream) {
    const float* x      = (const float*)d_in[0];
    const float* par    = (const float*)d_in[1];
    const int*   staind = (const int*)d_in[2];
    float*       out    = (float*)d_out;

    hipLaunchKernelGGL(hbv_kernel, dim3(NGRID / 4), dim3(64), 0, stream,
                       x, par, staind, out);
}